// Round 2
// baseline (741.701 us; speedup 1.0000x reference)
//
#include <hip/hip_runtime.h>

// ChebTimeConv: N=50000, E=1.6M, H=4, F_IN=F_OUT=32, K=4, Q=1.
// Features per node = H*F_IN = 128 fp32 (contiguous per node).
// Strategy: build CSR (by row) once per call -> 3 gather-only SpMMs ->
// progressive einsum accumulation into out (avoids storing all Tx_k).
// NOTE: harness delivers integer inputs as int32 (NOT int64 as in the
// reference) — edge_index is const int*.

#define FEAT 128   // H * F_IN
#define GOUT 32    // F_OUT

__global__ void count_kernel(const int* __restrict__ ei, int E, int* __restrict__ cnt) {
    int e = blockIdx.x * blockDim.x + threadIdx.x;
    if (e >= E) return;
    int r = ei[e];
    int c = ei[(size_t)E + e];
    if (r != c) atomicAdd(&cnt[r], 1);
}

// Single-block exclusive scan over N counts -> offsets[N+1]; also dinv[n].
__global__ void scan_kernel(const int* __restrict__ cnt, int* __restrict__ offsets,
                            float* __restrict__ dinv, int n) {
    __shared__ int buf[1024];
    __shared__ int carry_s;
    if (threadIdx.x == 0) carry_s = 0;
    __syncthreads();
    for (int base = 0; base < n; base += 1024) {
        int i = base + (int)threadIdx.x;
        int v = (i < n) ? cnt[i] : 0;
        buf[threadIdx.x] = v;
        __syncthreads();
        for (int off = 1; off < 1024; off <<= 1) {
            int t = (threadIdx.x >= (unsigned)off) ? buf[threadIdx.x - off] : 0;
            __syncthreads();
            buf[threadIdx.x] += t;
            __syncthreads();
        }
        int incl = buf[threadIdx.x];
        int carry = carry_s;
        if (i < n) {
            offsets[i] = carry + incl - v;          // exclusive
            dinv[i] = (v > 0) ? rsqrtf((float)v) : 0.0f;
        }
        __syncthreads();
        if (threadIdx.x == 1023) carry_s = carry + incl;
        __syncthreads();
    }
    if (threadIdx.x == 0) offsets[n] = carry_s;
}

__global__ void fill_kernel(const int* __restrict__ ei, const float* __restrict__ ew,
                            const int* __restrict__ offsets, int* __restrict__ cursor,
                            const float* __restrict__ dinv, int2* __restrict__ csr, int E) {
    int e = blockIdx.x * blockDim.x + threadIdx.x;
    if (e >= E) return;
    int r = ei[e];
    int c = ei[(size_t)E + e];
    if (r == c) return;                              // self loops: lap == 0, drop
    int pos = offsets[r] + atomicAdd(&cursor[r], 1);
    float lap = -dinv[r] * ew[e] * dinv[c];
    csr[pos] = make_int2(c, __float_as_int(lap));
}

// out = S(in)            (has_sub == 0)
// out = 2*S(in) - sub    (has_sub == 1)   [out may alias sub: per-element R-then-W]
// One wave (64 lanes) per node; lane handles 2 floats (float2).
__global__ void spmm_kernel(const float* __restrict__ in_t, const float* __restrict__ sub,
                            float* __restrict__ out_t, const int* __restrict__ offsets,
                            const int2* __restrict__ csr, int n, int has_sub) {
    int node = blockIdx.x * 4 + (threadIdx.x >> 6);
    if (node >= n) return;
    int lane = threadIdx.x & 63;
    int beg = offsets[node], end = offsets[node + 1];
    float ax = 0.f, ay = 0.f;
    int j = beg;
    for (; j + 4 <= end; j += 4) {
        int2 p0 = csr[j], p1 = csr[j + 1], p2 = csr[j + 2], p3 = csr[j + 3];
        float2 v0 = ((const float2*)(in_t + (size_t)p0.x * FEAT))[lane];
        float2 v1 = ((const float2*)(in_t + (size_t)p1.x * FEAT))[lane];
        float2 v2 = ((const float2*)(in_t + (size_t)p2.x * FEAT))[lane];
        float2 v3 = ((const float2*)(in_t + (size_t)p3.x * FEAT))[lane];
        float l0 = __int_as_float(p0.y), l1 = __int_as_float(p1.y);
        float l2 = __int_as_float(p2.y), l3 = __int_as_float(p3.y);
        ax += l0 * v0.x + l1 * v1.x + l2 * v2.x + l3 * v3.x;
        ay += l0 * v0.y + l1 * v1.y + l2 * v2.y + l3 * v3.y;
    }
    for (; j < end; ++j) {
        int2 p = csr[j];
        float2 v = ((const float2*)(in_t + (size_t)p.x * FEAT))[lane];
        float l = __int_as_float(p.y);
        ax += l * v.x;
        ay += l * v.y;
    }
    float2 o;
    if (has_sub) {
        float2 sv = ((const float2*)(sub + (size_t)node * FEAT))[lane];
        o.x = 2.f * ax - sv.x;
        o.y = 2.f * ay - sv.y;
    } else {
        o.x = ax;
        o.y = ay;
    }
    ((float2*)(out_t + (size_t)node * FEAT))[lane] = o;
}

// out[n,g] (+)= sum_i T[n,i] * Wk[i,g]  (+ bias[g] when init)
// Block 256 = 8 nodes x 32 outputs; Wk (16 KB) + 8 T-rows (4 KB) in LDS.
__global__ void einsum_kernel(const float* __restrict__ T, const float* __restrict__ Wk,
                              const float* __restrict__ bias, float* __restrict__ out,
                              int n, int init) {
    __shared__ float sW[FEAT * GOUT];
    __shared__ float sT[8 * FEAT];
    int nodeBase = blockIdx.x * 8;
    for (int idx = threadIdx.x; idx < FEAT * GOUT; idx += 256) sW[idx] = Wk[idx];
    for (int idx = threadIdx.x; idx < 8 * FEAT; idx += 256) {
        int nn = nodeBase + (idx >> 7);
        sT[idx] = (nn < n) ? T[(size_t)nn * FEAT + (idx & 127)] : 0.f;
    }
    __syncthreads();
    int g = threadIdx.x & 31;
    int nl = threadIdx.x >> 5;
    int node = nodeBase + nl;
    float acc = 0.f;
#pragma unroll
    for (int i = 0; i < FEAT; ++i) acc += sT[nl * FEAT + i] * sW[i * GOUT + g];
    if (node < n) {
        float* po = out + (size_t)node * GOUT + g;
        if (init) *po = acc + bias[g];
        else *po += acc;
    }
}

extern "C" void kernel_launch(void* const* d_in, const int* in_sizes, int n_in,
                              void* d_out, int out_size, void* d_ws, size_t ws_size,
                              hipStream_t stream) {
    const float* x = (const float*)d_in[0];
    const int* ei = (const int*)d_in[1];     // int32 per harness contract
    const float* ew = (const float*)d_in[2];
    const float* W = (const float*)d_in[3];
    const float* bias = (const float*)d_in[4];
    float* out = (float*)d_out;

    const int N = in_sizes[0] / FEAT;   // 50000
    const int E = in_sizes[1] / 2;      // 1600000

    char* p = (char*)d_ws;
    auto alloc = [&](size_t bytes) {
        char* q = p;
        p += (bytes + 255) & ~(size_t)255;
        return q;
    };
    int* cnt = (int*)alloc((size_t)N * 4);
    int* offsets = (int*)alloc(((size_t)N + 1) * 4);
    int* cursor = (int*)alloc((size_t)N * 4);
    float* dinv = (float*)alloc((size_t)N * 4);
    int2* csr = (int2*)alloc((size_t)E * 8);
    float* A = (float*)alloc((size_t)N * FEAT * 4);
    float* B = (float*)alloc((size_t)N * FEAT * 4);
    (void)ws_size;

    hipMemsetAsync(cnt, 0, (size_t)N * 4, stream);
    hipMemsetAsync(cursor, 0, (size_t)N * 4, stream);

    int eb = (E + 255) / 256;
    count_kernel<<<eb, 256, 0, stream>>>(ei, E, cnt);
    scan_kernel<<<1, 1024, 0, stream>>>(cnt, offsets, dinv, N);
    fill_kernel<<<eb, 256, 0, stream>>>(ei, ew, offsets, cursor, dinv, csr, E);

    int nb8 = (N + 7) / 8;
    int nb4 = (N + 3) / 4;
    // k=0: out = bias + x*W0
    einsum_kernel<<<nb8, 256, 0, stream>>>(x, W, bias, out, N, 1);
    // Tx1 = S(x)
    spmm_kernel<<<nb4, 256, 0, stream>>>(x, nullptr, A, offsets, csr, N, 0);
    einsum_kernel<<<nb8, 256, 0, stream>>>(A, W + 1 * FEAT * GOUT, bias, out, N, 0);
    // Tx2 = 2*S(Tx1) - x
    spmm_kernel<<<nb4, 256, 0, stream>>>(A, x, B, offsets, csr, N, 1);
    einsum_kernel<<<nb8, 256, 0, stream>>>(B, W + 2 * FEAT * GOUT, bias, out, N, 0);
    // Tx3 = 2*S(Tx2) - Tx1   (in-place over A: per-element read-then-write)
    spmm_kernel<<<nb4, 256, 0, stream>>>(B, A, A, offsets, csr, N, 1);
    einsum_kernel<<<nb8, 256, 0, stream>>>(A, W + 3 * FEAT * GOUT, bias, out, N, 0);
}

// Round 3
// 524.739 us; speedup vs baseline: 1.4135x; 1.4135x over previous
//
#include <hip/hip_runtime.h>

// ChebTimeConv: N=50000, E=1.6M, H=4, F_IN=F_OUT=32, K=4, Q=1.
// Features per node = H*F_IN = 128, contiguous per node.
// Pipeline: CSR build (count -> 2-level scan -> fill) -> 3 gather-only SpMMs
// over bf16 feature mirrors (fp32 accumulate) -> 4 small einsums into out.
// edge_index arrives as int32 (harness contract), not int64.

#define FEAT 128   // H * F_IN
#define GOUT 32    // F_OUT
#define SCB 256    // scan block size

typedef unsigned int uint;
typedef unsigned short ushort;

__device__ __forceinline__ ushort f2bf(float f) {
    uint u = __float_as_uint(f);
    return (ushort)((u + 0x7fffu + ((u >> 16) & 1u)) >> 16);   // RNE
}

__global__ void count_kernel(const int* __restrict__ ei, int E, int* __restrict__ cnt) {
    int e = blockIdx.x * blockDim.x + threadIdx.x;
    if (e >= E) return;
    int r = ei[e];
    int c = ei[(size_t)E + e];
    if (r != c) atomicAdd(&cnt[r], 1);
}

// Per-block inclusive scan; writes block-local exclusive prefix + block sum.
__global__ void scan1_kernel(const int* __restrict__ cnt, int* __restrict__ partial,
                             int* __restrict__ blockSums, int n) {
    __shared__ int buf[2][SCB];
    int t = threadIdx.x;
    int i = blockIdx.x * SCB + t;
    int v = (i < n) ? cnt[i] : 0;
    buf[0][t] = v;
    __syncthreads();
    int src = 0;
    for (int off = 1; off < SCB; off <<= 1) {
        int d = src ^ 1;
        buf[d][t] = buf[src][t] + ((t >= off) ? buf[src][t - off] : 0);
        __syncthreads();
        src = d;
    }
    int incl = buf[src][t];
    if (i < n) partial[i] = incl - v;
    if (t == SCB - 1) blockSums[blockIdx.x] = incl;
}

// Single block: exclusive scan of block sums; total -> *total_out.
__global__ void scan2_kernel(const int* __restrict__ blockSums, int* __restrict__ blockOffsets,
                             int nb, int* __restrict__ total_out) {
    __shared__ int buf[2][SCB];
    __shared__ int carry_s;
    if (threadIdx.x == 0) carry_s = 0;
    __syncthreads();
    for (int base = 0; base < nb; base += SCB) {
        int i = base + (int)threadIdx.x;
        int v = (i < nb) ? blockSums[i] : 0;
        buf[0][threadIdx.x] = v;
        __syncthreads();
        int src = 0;
        for (int off = 1; off < SCB; off <<= 1) {
            int d = src ^ 1;
            buf[d][threadIdx.x] = buf[src][threadIdx.x] +
                                  ((threadIdx.x >= (unsigned)off) ? buf[src][threadIdx.x - off] : 0);
            __syncthreads();
            src = d;
        }
        int incl = buf[src][threadIdx.x];
        int c = carry_s;
        if (i < nb) blockOffsets[i] = c + incl - v;
        __syncthreads();
        if (threadIdx.x == SCB - 1) carry_s = c + incl;
        __syncthreads();
    }
    if (threadIdx.x == 0) *total_out = carry_s;
}

__global__ void scan3_kernel(const int* __restrict__ cnt, const int* __restrict__ partial,
                             const int* __restrict__ blockOffsets, int* __restrict__ offsets,
                             float* __restrict__ dinv, int n) {
    int i = blockIdx.x * blockDim.x + threadIdx.x;
    if (i >= n) return;
    offsets[i] = partial[i] + blockOffsets[i / SCB];
    int v = cnt[i];
    dinv[i] = (v > 0) ? rsqrtf((float)v) : 0.0f;
}

__global__ void fill_kernel(const int* __restrict__ ei, const float* __restrict__ ew,
                            const int* __restrict__ offsets, int* __restrict__ cursor,
                            const float* __restrict__ dinv, int2* __restrict__ csr, int E) {
    int e = blockIdx.x * blockDim.x + threadIdx.x;
    if (e >= E) return;
    int r = ei[e];
    int c = ei[(size_t)E + e];
    if (r == c) return;                              // self loop: lap == 0, drop
    int pos = offsets[r] + atomicAdd(&cursor[r], 1);
    float lap = -dinv[r] * ew[e] * dinv[c];
    csr[pos] = make_int2(c, __float_as_int(lap));
}

// x (fp32) -> xb (bf16), 4 elements/thread.
__global__ void cvt_kernel(const float* __restrict__ x, ushort* __restrict__ xb, int n4) {
    int i = blockIdx.x * blockDim.x + threadIdx.x;
    if (i >= n4) return;
    float4 v = ((const float4*)x)[i];
    ushort4 o;
    o.x = f2bf(v.x); o.y = f2bf(v.y); o.z = f2bf(v.z); o.w = f2bf(v.w);
    ((ushort4*)xb)[i] = o;
}

// out = S(in)          (has_sub == 0)
// out = 2*S(in) - sub  (has_sub == 1)  [out may alias sub: per-lane R-then-W;
//                                       gathers never touch sub/out buffer]
// One wave per node; lane handles feats [2*lane, 2*lane+1] (one packed uint).
// All feature buffers are bf16; accumulation is fp32.
__global__ void spmm_kernel(const ushort* __restrict__ inb, const ushort* __restrict__ sub,
                            ushort* __restrict__ outb, const int* __restrict__ offsets,
                            const int2* __restrict__ csr, int n, int has_sub) {
    int node = blockIdx.x * 4 + (threadIdx.x >> 6);
    if (node >= n) return;
    int lane = threadIdx.x & 63;
    int beg = offsets[node], end = offsets[node + 1];
    float ax = 0.f, ay = 0.f;
    int j = beg;
    for (; j + 4 <= end; j += 4) {
        int2 p0 = csr[j], p1 = csr[j + 1], p2 = csr[j + 2], p3 = csr[j + 3];
        uint u0 = ((const uint*)(inb + (size_t)p0.x * FEAT))[lane];
        uint u1 = ((const uint*)(inb + (size_t)p1.x * FEAT))[lane];
        uint u2 = ((const uint*)(inb + (size_t)p2.x * FEAT))[lane];
        uint u3 = ((const uint*)(inb + (size_t)p3.x * FEAT))[lane];
        float l0 = __int_as_float(p0.y), l1 = __int_as_float(p1.y);
        float l2 = __int_as_float(p2.y), l3 = __int_as_float(p3.y);
        ax += l0 * __uint_as_float(u0 << 16) + l1 * __uint_as_float(u1 << 16)
            + l2 * __uint_as_float(u2 << 16) + l3 * __uint_as_float(u3 << 16);
        ay += l0 * __uint_as_float(u0 & 0xffff0000u) + l1 * __uint_as_float(u1 & 0xffff0000u)
            + l2 * __uint_as_float(u2 & 0xffff0000u) + l3 * __uint_as_float(u3 & 0xffff0000u);
    }
    for (; j < end; ++j) {
        int2 p = csr[j];
        uint u = ((const uint*)(inb + (size_t)p.x * FEAT))[lane];
        float l = __int_as_float(p.y);
        ax += l * __uint_as_float(u << 16);
        ay += l * __uint_as_float(u & 0xffff0000u);
    }
    float ox = ax, oy = ay;
    if (has_sub) {
        uint s = ((const uint*)(sub + (size_t)node * FEAT))[lane];
        ox = 2.f * ax - __uint_as_float(s << 16);
        oy = 2.f * ay - __uint_as_float(s & 0xffff0000u);
    }
    uint o = (uint)f2bf(ox) | ((uint)f2bf(oy) << 16);
    ((uint*)(outb + (size_t)node * FEAT))[lane] = o;
}

// out[n,g] (+)= sum_i T[n,i] * Wk[i,g]  (+ bias[g] when init). T is bf16.
// Block 256 = 8 nodes x 32 outputs; Wk (16 KB) + 8 T-rows (4 KB) in LDS.
__global__ void einsum_kernel(const ushort* __restrict__ T, const float* __restrict__ Wk,
                              const float* __restrict__ bias, float* __restrict__ out,
                              int n, int init) {
    __shared__ float sW[FEAT * GOUT];
    __shared__ float sT[8 * FEAT];
    int nodeBase = blockIdx.x * 8;
    for (int idx = threadIdx.x; idx < FEAT * GOUT; idx += 256) sW[idx] = Wk[idx];
    // 8*128 = 1024 bf16 = 512 packed uints
    for (int idx = threadIdx.x; idx < 8 * FEAT / 2; idx += 256) {
        int nn = nodeBase + (idx >> 6);              // 64 uints per node
        uint u = 0;
        if (nn < n) u = ((const uint*)(T + (size_t)nn * FEAT))[idx & 63];
        sT[2 * idx]     = __uint_as_float(u << 16);
        sT[2 * idx + 1] = __uint_as_float(u & 0xffff0000u);
    }
    __syncthreads();
    int g = threadIdx.x & 31;
    int nl = threadIdx.x >> 5;
    int node = nodeBase + nl;
    float acc = 0.f;
#pragma unroll
    for (int i = 0; i < FEAT; ++i) acc += sT[nl * FEAT + i] * sW[i * GOUT + g];
    if (node < n) {
        float* po = out + (size_t)node * GOUT + g;
        if (init) *po = acc + bias[g];
        else *po += acc;
    }
}

extern "C" void kernel_launch(void* const* d_in, const int* in_sizes, int n_in,
                              void* d_out, int out_size, void* d_ws, size_t ws_size,
                              hipStream_t stream) {
    const float* x = (const float*)d_in[0];
    const int* ei = (const int*)d_in[1];     // int32 per harness contract
    const float* ew = (const float*)d_in[2];
    const float* W = (const float*)d_in[3];
    const float* bias = (const float*)d_in[4];
    float* out = (float*)d_out;

    const int N = in_sizes[0] / FEAT;   // 50000
    const int E = in_sizes[1] / 2;      // 1600000
    const int NB = (N + SCB - 1) / SCB; // scan blocks (196)

    char* p = (char*)d_ws;
    auto alloc = [&](size_t bytes) {
        char* q = p;
        p += (bytes + 255) & ~(size_t)255;
        return q;
    };
    int* cnt = (int*)alloc((size_t)N * 4);
    int* offsets = (int*)alloc(((size_t)N + 1) * 4);
    int* cursor = (int*)alloc((size_t)N * 4);
    float* dinv = (float*)alloc((size_t)N * 4);
    int* partial = (int*)alloc((size_t)N * 4);
    int* blockSums = (int*)alloc((size_t)NB * 4);
    int* blockOffsets = (int*)alloc((size_t)NB * 4);
    int2* csr = (int2*)alloc((size_t)E * 8);
    ushort* xb = (ushort*)alloc((size_t)N * FEAT * 2);
    ushort* Ab = (ushort*)alloc((size_t)N * FEAT * 2);
    ushort* Bb = (ushort*)alloc((size_t)N * FEAT * 2);
    (void)ws_size;

    hipMemsetAsync(cnt, 0, (size_t)N * 4, stream);
    hipMemsetAsync(cursor, 0, (size_t)N * 4, stream);

    int eb = (E + 255) / 256;
    count_kernel<<<eb, 256, 0, stream>>>(ei, E, cnt);
    scan1_kernel<<<NB, SCB, 0, stream>>>(cnt, partial, blockSums, N);
    scan2_kernel<<<1, SCB, 0, stream>>>(blockSums, blockOffsets, NB, offsets + N);
    scan3_kernel<<<NB, SCB, 0, stream>>>(cnt, partial, blockOffsets, offsets, dinv, N);
    fill_kernel<<<eb, 256, 0, stream>>>(ei, ew, offsets, cursor, dinv, csr, E);

    int n4 = N * FEAT / 4;
    cvt_kernel<<<(n4 + 255) / 256, 256, 0, stream>>>(x, xb, n4);

    int nb8 = (N + 7) / 8;
    int nb4 = (N + 3) / 4;
    // k=0: out = bias + x*W0
    einsum_kernel<<<nb8, 256, 0, stream>>>(xb, W, bias, out, N, 1);
    // Tx1 = S(x)
    spmm_kernel<<<nb4, 256, 0, stream>>>(xb, nullptr, Ab, offsets, csr, N, 0);
    einsum_kernel<<<nb8, 256, 0, stream>>>(Ab, W + 1 * FEAT * GOUT, bias, out, N, 0);
    // Tx2 = 2*S(Tx1) - x
    spmm_kernel<<<nb4, 256, 0, stream>>>(Ab, xb, Bb, offsets, csr, N, 1);
    einsum_kernel<<<nb8, 256, 0, stream>>>(Bb, W + 2 * FEAT * GOUT, bias, out, N, 0);
    // Tx3 = 2*S(Tx2) - Tx1   (out aliases sub; gathers read Bb only)
    spmm_kernel<<<nb4, 256, 0, stream>>>(Bb, Ab, Ab, offsets, csr, N, 1);
    einsum_kernel<<<nb8, 256, 0, stream>>>(Ab, W + 3 * FEAT * GOUT, bias, out, N, 0);
}

// Round 4
// 500.116 us; speedup vs baseline: 1.4831x; 1.0492x over previous
//
#include <hip/hip_runtime.h>

// ChebTimeConv: N=50000, E=1.6M, H=4, F_IN=F_OUT=32, K=4, Q=1.
// Pipeline: count -> 2-level scan -> fill (XCD-range-split, packed 4B CSR)
//        -> cvt+einsum0 fused -> 3x spmm with fused einsum epilogue.
// Feature mirrors are bf16 (fp32 accumulate). edge_index arrives int32.
// CSR entry: (col << 16) | bf16(lap)  -- valid since N < 65536.

#define FEAT 128   // H * F_IN
#define GOUT 32    // F_OUT
#define SCB 256    // scan block size
#define WPB 8      // nodes (=waves) per spmm block
#define FILLCH 4096

typedef unsigned int uint;
typedef unsigned short ushort;

__device__ __forceinline__ ushort f2bf(float f) {
    uint u = __float_as_uint(f);
    return (ushort)((u + 0x7fffu + ((u >> 16) & 1u)) >> 16);   // RNE
}
__device__ __forceinline__ float bflo(uint u) { return __uint_as_float(u << 16); }
__device__ __forceinline__ float bfhi(uint u) { return __uint_as_float(u & 0xffff0000u); }

// ---- degree count, row-range split so atomics localize per XCD ----
__global__ void count_kernel(const int* __restrict__ ei, int E, int* __restrict__ cnt,
                             int rchunk) {
    int rlo = (blockIdx.x & 7) * rchunk, rhi = rlo + rchunk;
    int e0 = (blockIdx.x >> 3) * FILLCH;
    int e1 = min(e0 + FILLCH, E);
    for (int e = e0 + (int)threadIdx.x; e < e1; e += 256) {
        int r = ei[e];
        if (r < rlo || r >= rhi) continue;
        int c = ei[(size_t)E + e];
        if (r != c) atomicAdd(&cnt[r], 1);
    }
}

// ---- two-level scan ----
__global__ void scan1_kernel(const int* __restrict__ cnt, int* __restrict__ partial,
                             int* __restrict__ blockSums, int n) {
    __shared__ int buf[2][SCB];
    int t = threadIdx.x;
    int i = blockIdx.x * SCB + t;
    int v = (i < n) ? cnt[i] : 0;
    buf[0][t] = v;
    __syncthreads();
    int src = 0;
    for (int off = 1; off < SCB; off <<= 1) {
        int d = src ^ 1;
        buf[d][t] = buf[src][t] + ((t >= off) ? buf[src][t - off] : 0);
        __syncthreads();
        src = d;
    }
    int incl = buf[src][t];
    if (i < n) partial[i] = incl - v;
    if (t == SCB - 1) blockSums[blockIdx.x] = incl;
}

__global__ void scan2_kernel(const int* __restrict__ blockSums, int* __restrict__ blockOffsets,
                             int nb, int* __restrict__ total_out) {
    __shared__ int buf[2][SCB];
    __shared__ int carry_s;
    if (threadIdx.x == 0) carry_s = 0;
    __syncthreads();
    for (int base = 0; base < nb; base += SCB) {
        int i = base + (int)threadIdx.x;
        int v = (i < nb) ? blockSums[i] : 0;
        buf[0][threadIdx.x] = v;
        __syncthreads();
        int src = 0;
        for (int off = 1; off < SCB; off <<= 1) {
            int d = src ^ 1;
            buf[d][threadIdx.x] = buf[src][threadIdx.x] +
                                  ((threadIdx.x >= (unsigned)off) ? buf[src][threadIdx.x - off] : 0);
            __syncthreads();
            src = d;
        }
        int incl = buf[src][threadIdx.x];
        int c = carry_s;
        if (i < nb) blockOffsets[i] = c + incl - v;
        __syncthreads();
        if (threadIdx.x == SCB - 1) carry_s = c + incl;
        __syncthreads();
    }
    if (threadIdx.x == 0) *total_out = carry_s;
}

__global__ void scan3_kernel(const int* __restrict__ cnt, const int* __restrict__ partial,
                             const int* __restrict__ blockOffsets, int* __restrict__ offsets,
                             float* __restrict__ dinv, int n) {
    int i = blockIdx.x * blockDim.x + threadIdx.x;
    if (i >= n) return;
    offsets[i] = partial[i] + blockOffsets[i / SCB];
    int v = cnt[i];
    dinv[i] = (v > 0) ? rsqrtf((float)v) : 0.0f;
}

// ---- CSR fill: row-range split (one XCD owns each 0.8 MB csr window) ----
__global__ void fill_kernel(const int* __restrict__ ei, const float* __restrict__ ew,
                            const int* __restrict__ offsets, int* __restrict__ cursor,
                            const float* __restrict__ dinv, uint* __restrict__ csr,
                            int E, int rchunk) {
    int rlo = (blockIdx.x & 7) * rchunk, rhi = rlo + rchunk;
    int e0 = (blockIdx.x >> 3) * FILLCH;
    int e1 = min(e0 + FILLCH, E);
    for (int e = e0 + (int)threadIdx.x; e < e1; e += 256) {
        int r = ei[e];
        if (r < rlo || r >= rhi) continue;
        int c = ei[(size_t)E + e];
        if (r == c) continue;                        // self loop: lap == 0, drop
        int pos = offsets[r] + atomicAdd(&cursor[r], 1);
        float lap = -dinv[r] * ew[e] * dinv[c];
        csr[pos] = ((uint)c << 16) | (uint)f2bf(lap);
    }
}

// ---- fused: x -> bf16 mirror, plus out = bias + x*W0 (init) ----
// block 256 = 8 nodes; 2 nodes per wave, 32 threads/node (q=g-quad, part=i-range).
__global__ __launch_bounds__(256) void cvt_einsum0_kernel(
    const float* __restrict__ x, ushort* __restrict__ xb,
    const float* __restrict__ W0, const float* __restrict__ bias,
    float* __restrict__ out, int n) {
    __shared__ __align__(16) float4 sW4[FEAT * GOUT / 4];
    __shared__ __align__(16) float sT[8 * FEAT];
    const float* sW = (const float*)sW4;
    int t = threadIdx.x;
    const float4* wsrc = (const float4*)W0;
    for (int idx = t; idx < FEAT * GOUT / 4; idx += 256) sW4[idx] = wsrc[idx];
    size_t gi = (size_t)blockIdx.x * (8 * FEAT) + (size_t)t * 4;
    float4 v = make_float4(0.f, 0.f, 0.f, 0.f);
    bool inb = gi < (size_t)n * FEAT;
    if (inb) v = *(const float4*)(x + gi);
    if (inb) {
        ushort4 o;
        o.x = f2bf(v.x); o.y = f2bf(v.y); o.z = f2bf(v.z); o.w = f2bf(v.w);
        *(ushort4*)(xb + gi) = o;
    }
    *(float4*)&sT[t * 4] = v;
    __syncthreads();
    int nl = t >> 5;            // node 0..7 in block
    int l32 = t & 31;
    int q = l32 & 7;            // g = 4q..4q+3
    int part = l32 >> 3;        // i in [part*32, part*32+32)
    float tv[32];
#pragma unroll
    for (int j = 0; j < 8; ++j) {
        float4 t4 = *(const float4*)&sT[nl * FEAT + part * 32 + 4 * j];
        tv[4 * j] = t4.x; tv[4 * j + 1] = t4.y; tv[4 * j + 2] = t4.z; tv[4 * j + 3] = t4.w;
    }
    float4 a4 = make_float4(0.f, 0.f, 0.f, 0.f);
#pragma unroll
    for (int j = 0; j < 32; ++j) {
        int i = part * 32 + j;
        float4 wv = *(const float4*)&sW[i * GOUT + 4 * q];
        a4.x += tv[j] * wv.x; a4.y += tv[j] * wv.y;
        a4.z += tv[j] * wv.z; a4.w += tv[j] * wv.w;
    }
    a4.x += __shfl_down(a4.x, 8);  a4.y += __shfl_down(a4.y, 8);
    a4.z += __shfl_down(a4.z, 8);  a4.w += __shfl_down(a4.w, 8);
    a4.x += __shfl_down(a4.x, 16); a4.y += __shfl_down(a4.y, 16);
    a4.z += __shfl_down(a4.z, 16); a4.w += __shfl_down(a4.w, 16);
    int node = blockIdx.x * 8 + nl;
    if (part == 0 && node < n) {
        const float4 b4 = *(const float4*)(bias + 4 * q);
        float4 r;
        r.x = a4.x + b4.x; r.y = a4.y + b4.y; r.z = a4.z + b4.z; r.w = a4.w + b4.w;
        *(float4*)(out + (size_t)node * GOUT + 4 * q) = r;
    }
}

// ---- SpMM (one wave per node) with fused einsum epilogue ----
// outb = S(in) or 2*S(in) - sub (bf16); out[node,:] += T_fp32 . Wk
__global__ __launch_bounds__(512) void spmm_fused_kernel(
    const ushort* __restrict__ inb, const ushort* __restrict__ sub,
    ushort* __restrict__ outb, const int* __restrict__ offsets,
    const uint* __restrict__ csr, const float* __restrict__ Wk,
    float* __restrict__ out, int n, int has_sub) {
    __shared__ __align__(16) float4 sW4[FEAT * GOUT / 4];   // 16 KB
    __shared__ __align__(16) float sT[WPB][FEAT];           // 4 KB
    const float* sW = (const float*)sW4;
    int w = threadIdx.x >> 6;
    int lane = threadIdx.x & 63;
    int node = blockIdx.x * WPB + w;
    const float4* wsrc = (const float4*)Wk;
    for (int idx = threadIdx.x; idx < FEAT * GOUT / 4; idx += 512) sW4[idx] = wsrc[idx];
    float ox = 0.f, oy = 0.f;
    if (node < n) {
        int beg = offsets[node], end = offsets[node + 1];
        float ax = 0.f, ay = 0.f;
        int j = beg;
        for (; j + 4 <= end; j += 4) {
            uint q0 = csr[j], q1 = csr[j + 1], q2 = csr[j + 2], q3 = csr[j + 3];
            uint u0 = ((const uint*)(inb + (size_t)(q0 >> 16) * FEAT))[lane];
            uint u1 = ((const uint*)(inb + (size_t)(q1 >> 16) * FEAT))[lane];
            uint u2 = ((const uint*)(inb + (size_t)(q2 >> 16) * FEAT))[lane];
            uint u3 = ((const uint*)(inb + (size_t)(q3 >> 16) * FEAT))[lane];
            float l0 = bflo(q0), l1 = bflo(q1), l2 = bflo(q2), l3 = bflo(q3);
            ax += l0 * bflo(u0) + l1 * bflo(u1) + l2 * bflo(u2) + l3 * bflo(u3);
            ay += l0 * bfhi(u0) + l1 * bfhi(u1) + l2 * bfhi(u2) + l3 * bfhi(u3);
        }
        for (; j < end; ++j) {
            uint qe = csr[j];
            uint u = ((const uint*)(inb + (size_t)(qe >> 16) * FEAT))[lane];
            float l = bflo(qe);
            ax += l * bflo(u);
            ay += l * bfhi(u);
        }
        ox = ax; oy = ay;
        if (has_sub) {
            uint s = ((const uint*)(sub + (size_t)node * FEAT))[lane];
            ox = 2.f * ax - bflo(s);
            oy = 2.f * ay - bfhi(s);
        }
        ((uint*)(outb + (size_t)node * FEAT))[lane] = (uint)f2bf(ox) | ((uint)f2bf(oy) << 16);
    }
    *(float2*)&sT[w][2 * lane] = make_float2(ox, oy);
    __syncthreads();
    // epilogue: out[node, 4q..4q+3] += sum_i T[i] * Wk[i, 4q..4q+3]
    int q = lane & 7;           // g quad
    int part = lane >> 3;       // i in [part*16, part*16+16)
    float tv[16];
#pragma unroll
    for (int j = 0; j < 4; ++j) {
        float4 t4 = *(const float4*)&sT[w][part * 16 + 4 * j];
        tv[4 * j] = t4.x; tv[4 * j + 1] = t4.y; tv[4 * j + 2] = t4.z; tv[4 * j + 3] = t4.w;
    }
    float4 a4 = make_float4(0.f, 0.f, 0.f, 0.f);
#pragma unroll
    for (int j = 0; j < 16; ++j) {
        int i = part * 16 + j;
        float4 wv = *(const float4*)&sW[i * GOUT + 4 * q];
        a4.x += tv[j] * wv.x; a4.y += tv[j] * wv.y;
        a4.z += tv[j] * wv.z; a4.w += tv[j] * wv.w;
    }
#pragma unroll
    for (int off = 8; off < 64; off <<= 1) {
        a4.x += __shfl_down(a4.x, off);
        a4.y += __shfl_down(a4.y, off);
        a4.z += __shfl_down(a4.z, off);
        a4.w += __shfl_down(a4.w, off);
    }
    if (part == 0 && node < n) {
        float4* po = (float4*)(out + (size_t)node * GOUT + 4 * q);
        float4 cur = *po;
        cur.x += a4.x; cur.y += a4.y; cur.z += a4.z; cur.w += a4.w;
        *po = cur;
    }
}

extern "C" void kernel_launch(void* const* d_in, const int* in_sizes, int n_in,
                              void* d_out, int out_size, void* d_ws, size_t ws_size,
                              hipStream_t stream) {
    const float* x = (const float*)d_in[0];
    const int* ei = (const int*)d_in[1];     // int32 per harness contract
    const float* ew = (const float*)d_in[2];
    const float* W = (const float*)d_in[3];
    const float* bias = (const float*)d_in[4];
    float* out = (float*)d_out;

    const int N = in_sizes[0] / FEAT;   // 50000
    const int E = in_sizes[1] / 2;      // 1600000
    const int NB = (N + SCB - 1) / SCB;
    const int rchunk = (N + 7) / 8;

    char* p = (char*)d_ws;
    auto alloc = [&](size_t bytes) {
        char* q = p;
        p += (bytes + 255) & ~(size_t)255;
        return q;
    };
    int* cnt = (int*)alloc((size_t)N * 4);
    int* offsets = (int*)alloc(((size_t)N + 1) * 4);
    int* cursor = (int*)alloc((size_t)N * 4);
    float* dinv = (float*)alloc((size_t)N * 4);
    int* partial = (int*)alloc((size_t)N * 4);
    int* blockSums = (int*)alloc((size_t)NB * 4);
    int* blockOffsets = (int*)alloc((size_t)NB * 4);
    uint* csr = (uint*)alloc((size_t)E * 4);
    ushort* xb = (ushort*)alloc((size_t)N * FEAT * 2);
    ushort* Ab = (ushort*)alloc((size_t)N * FEAT * 2);
    ushort* Bb = (ushort*)alloc((size_t)N * FEAT * 2);
    (void)ws_size;

    hipMemsetAsync(cnt, 0, (size_t)N * 4, stream);
    hipMemsetAsync(cursor, 0, (size_t)N * 4, stream);

    int fgrid = ((E + FILLCH - 1) / FILLCH) * 8;
    count_kernel<<<fgrid, 256, 0, stream>>>(ei, E, cnt, rchunk);
    scan1_kernel<<<NB, SCB, 0, stream>>>(cnt, partial, blockSums, N);
    scan2_kernel<<<1, SCB, 0, stream>>>(blockSums, blockOffsets, NB, offsets + N);
    scan3_kernel<<<NB, SCB, 0, stream>>>(cnt, partial, blockOffsets, offsets, dinv, N);
    fill_kernel<<<fgrid, 256, 0, stream>>>(ei, ew, offsets, cursor, dinv, csr, E, rchunk);

    // out = bias + x*W0 ; xb = bf16(x)
    cvt_einsum0_kernel<<<(N + 7) / 8, 256, 0, stream>>>(x, xb, W, bias, out, N);

    int sg = (N + WPB - 1) / WPB;
    // Tx1 = S(x);            out += Tx1*W1
    spmm_fused_kernel<<<sg, 512, 0, stream>>>(xb, nullptr, Ab, offsets, csr,
                                              W + 1 * FEAT * GOUT, out, N, 0);
    // Tx2 = 2*S(Tx1) - x;    out += Tx2*W2
    spmm_fused_kernel<<<sg, 512, 0, stream>>>(Ab, xb, Bb, offsets, csr,
                                              W + 2 * FEAT * GOUT, out, N, 1);
    // Tx3 = 2*S(Tx2) - Tx1;  out += Tx3*W3   (outb aliases sub; read-before-write)
    spmm_fused_kernel<<<sg, 512, 0, stream>>>(Bb, Ab, Ab, offsets, csr,
                                              W + 3 * FEAT * GOUT, out, N, 1);
}